// Round 3
// baseline (865.830 us; speedup 1.0000x reference)
//
#include <hip/hip_runtime.h>
#include <math.h>

#define N_NODES 100000
#define N_EDGES 3200000
#define KH 48            // K*H active channels
#define FDIM 64          // padded feature row stride (128 B, line-aligned)
#define NH 16            // H
#define BN_EPS 1e-5f
#define NBUCK 196        // ceil(100000/512) buckets of 512 nodes
#define BSHIFT 9
#define BMASK 511
#define EPB 16384        // edges per block in bucket scatter
#define NBLK1 196        // ceil(N_EDGES/EPB)
#define CAP 18432        // fixed bucket capacity: mean 16327 + 16 sigma
#define FIX 16777216.0f  // 2^24 fixed point for degree sums

typedef unsigned long long u64;
typedef unsigned int u32;
typedef unsigned short u16;

__device__ __forceinline__ u16 f2bf(float f) {
  u32 b = __float_as_uint(f);
  b += 0x7FFFu + ((b >> 16) & 1u);   // RNE
  return (u16)(b >> 16);
}
__device__ __forceinline__ float bf2f(u32 s) {
  return __uint_as_float(s << 16);
}

// ---------------- K1: scatter edges into FIXED-CAPACITY buckets -------------
__global__ __launch_bounds__(1024) void bucket_scatter_kernel(
    const int* __restrict__ row, const int* __restrict__ col,
    const float* __restrict__ ea, u32* __restrict__ gcur,
    int2* __restrict__ bucketed) {
  __shared__ u32 bins[NBUCK];
  __shared__ u32 base[NBUCK];
  __shared__ u16 rnk[EPB];
  for (int t = threadIdx.x; t < NBUCK; t += 1024) bins[t] = 0;
  __syncthreads();
  int eb = blockIdx.x * EPB;
  for (int it = 0; it < EPB / 1024; ++it) {
    int i = it * 1024 + threadIdx.x;
    int e = eb + i;
    if (e < N_EDGES) rnk[i] = (u16)atomicAdd(&bins[col[e] >> BSHIFT], 1u);
  }
  __syncthreads();
  for (int t = threadIdx.x; t < NBUCK; t += 1024) {
    u32 c = bins[t];
    if (c) base[t] = (u32)t * CAP + atomicAdd(&gcur[t * 8], c);
  }
  __syncthreads();
  for (int it = 0; it < EPB / 1024; ++it) {
    int i = it * 1024 + threadIdx.x;
    int e = eb + i;
    if (e < N_EDGES) {
      int c = col[e];
      int bkt = c >> BSHIFT, cl = c & BMASK;
      u32 pos = base[bkt] + (u32)rnk[i];
      bucketed[pos] = make_int2((cl << 17) | row[e], __float_as_int(ea[e]));
    }
  }
}

// ---------------- P2a: per-bucket node counts -> offs, dinv, zx -------------
__global__ __launch_bounds__(1024) void node_offs_kernel(
    const int2* __restrict__ bucketed, const u32* __restrict__ gcur,
    const float* __restrict__ x,
    int* __restrict__ offs, float* __restrict__ dinv, u16* __restrict__ zx) {
  __shared__ u32 cnt[512];
  __shared__ u32 degf[512];
  __shared__ u32 red[256];
  __shared__ u32 shmeta[2];   // [0]=bstart, [1]=fill
  int t = threadIdx.x;
  int b = blockIdx.x;
  if (t < 512) { cnt[t] = 0; degf[t] = 0; }
  if (t < 256) red[t] = (t < b) ? gcur[t * 8] : 0;   // NBUCK<256
  __syncthreads();
  for (int d = 128; d; d >>= 1) {
    if (t < d) red[t] += red[t + d];
    __syncthreads();
  }
  if (t == 0) { shmeta[0] = red[0]; shmeta[1] = gcur[b * 8]; }
  __syncthreads();
  u32 bst = shmeta[0], fill = shmeta[1];
  u32 s_pad = (u32)b * CAP;
  for (u32 i = t; i < fill; i += 1024) {
    int2 v = bucketed[s_pad + i];
    int cl = (v.x >> 17) & BMASK;
    atomicAdd(&cnt[cl], 1u);
    atomicAdd(&degf[cl], (u32)(__int_as_float(v.y) * FIX));
  }
  __syncthreads();
  u32 v0 = (t < 512) ? cnt[t] : 0;
  for (int d = 1; d < 512; d <<= 1) {
    u32 u = (t < 512 && t >= d) ? cnt[t - d] : 0;
    __syncthreads();
    if (t < 512) cnt[t] += u;
    __syncthreads();
  }
  int n = b * 512 + t;
  if (t < 512 && n < N_NODES) {
    offs[n] = (int)(bst + cnt[t] - v0);  // exclusive, compact
    float dg = (float)degf[t] * (1.0f / FIX);
    float dv = dg > 0.f ? rsqrtf(fmaxf(dg, 1e-12f)) : 0.f;
    dinv[n] = dv;
    zx[n] = f2bf(x[n] * dv);
  }
  if (b == 0 && t == 0) offs[N_NODES] = N_EDGES;
}

// ---------------- P2b: packed 4B CSR: (src<<15) | bf16(ea) ------------------
__global__ __launch_bounds__(1024) void csr_fill_kernel(
    const int2* __restrict__ bucketed, const u32* __restrict__ gcur,
    const int* __restrict__ offs, u32* __restrict__ csr) {
  __shared__ u32 cur[512];
  __shared__ u32 shfill;
  int t = threadIdx.x;
  int b = blockIdx.x;
  int n = b * 512 + t;
  if (t < 512) cur[t] = (n < N_NODES) ? (u32)offs[n] : 0;
  if (t == 0) shfill = gcur[b * 8];
  __syncthreads();
  u32 fill = shfill;
  u32 s_pad = (u32)b * CAP;
  for (u32 i = t; i < fill; i += 1024) {
    int2 v = bucketed[s_pad + i];
    int cl = (v.x >> 17) & BMASK;
    u32 r = (u32)(v.x & 0x1FFFF);
    u16 w = f2bf(__int_as_float(v.y));   // ea >= 0 -> sign bit 0, w < 0x8000
    u32 pos = atomicAdd(&cur[cl], 1u);
    csr[pos] = (r << 15) | (u32)w;
  }
}

// ---------------- layer-1: scalar prop + epilogue + transform (merged) ------
__global__ __launch_bounds__(256) void sprop_mid_kernel(
    const u32* __restrict__ csr, const int* __restrict__ offs,
    const u16* __restrict__ zx, const float* __restrict__ dinv,
    const float* __restrict__ x,
    const float* __restrict__ w1i, const float* __restrict__ w1r,
    const float* __restrict__ b1, const float* __restrict__ w1,
    u16* __restrict__ tout) {
  int t = blockIdx.x * 256 + threadIdx.x;
  int n = t >> 4, c = t & 15;
  float a = 0.f;
  int s = offs[n], e = offs[n + 1];
  for (int i = s + c; i < e; i += 16) {
    u32 ee = csr[i];
    a += bf2f(ee & 0x7FFFu) * bf2f((u32)zx[ee >> 15]);
  }
#pragma unroll
  for (int o = 8; o; o >>= 1) a += __shfl_xor(a, o, 64);
  float dn = dinv[n];
  float sn = a * dn;
  float xn = x[n];
  int base = (threadIdx.x & 63) & 48;
#pragma unroll
  for (int k = 0; k < 3; ++k) {
    float u = fmaxf(sn * w1i[k * 16 + c] + xn * w1r[k * 16 + c] + b1[k * 16 + c], 0.f);
    float tf = 0.f;
#pragma unroll
    for (int f = 0; f < 16; ++f) tf += __shfl(u, base + f, 64) * w1[k * 256 + f * 16 + c];
    tout[(size_t)n * FDIM + k * 16 + c] = f2bf(tf * dn);
  }
}

// ---------------- conv1 propagate, all 3 stacks combined --------------------
// wave per node, lane = channel, 48 active; rows 128 B line-aligned.
// Lane-striped csr chunks (64 edges / VMEM instr) broadcast via shfl,
// with next-chunk prefetch. Gathers stay 16-deep, wave-wide coalesced.
__global__ __launch_bounds__(256) void conv1_prop_kernel(
    const u16* __restrict__ tin, u16* __restrict__ tout, float* __restrict__ hbuf,
    const u32* __restrict__ csr, const int* __restrict__ offs,
    const float* __restrict__ dinv, const float* __restrict__ x,
    const float* __restrict__ w1r, const float* __restrict__ b1,
    const float* __restrict__ w1, int do_t) {
  int lane = threadIdx.x & 63;
  int wid = (blockIdx.x * blockDim.x + threadIdx.x) >> 6;
  int nw = (gridDim.x * blockDim.x) >> 6;
  int c = lane;
  bool act = c < KH;
  float rb = act ? w1r[c] : 0.f;
  float bb = act ? b1[c] : 0.f;
  float wreg[16];
  if (do_t) {
    int k = c >> 4, o = c & 15;
    if (act) {
#pragma unroll
      for (int f = 0; f < 16; ++f) wreg[f] = w1[k * 256 + f * 16 + o];
    } else {
#pragma unroll
      for (int f = 0; f < 16; ++f) wreg[f] = 0.f;
    }
  }
  for (int n = wid; n < N_NODES; n += nw) {
    int nu = __builtin_amdgcn_readfirstlane(n);
    int s = offs[nu], e = offs[nu + 1];
    float acc = 0.f;
    int i = s;
    if (i < e) {
      int idx = i + lane;
      if (idx >= e) idx = e - 1;
      u32 cv = __builtin_nontemporal_load(csr + idx);
      while (true) {
        int cnt = (e - i < 64) ? (e - i) : 64;
        bool more = (i + 64) < e;
        u32 cvn = 0;
        if (more) {
          int idx2 = i + 64 + lane;
          if (idx2 >= e) idx2 = e - 1;
          cvn = __builtin_nontemporal_load(csr + idx2);
        }
        int j = 0;
        for (; j + 16 <= cnt; j += 16) {
#pragma unroll
          for (int u = 0; u < 16; ++u) {
            u32 ee = __shfl(cv, j + u, 64);
            if (act) acc += bf2f(ee & 0x7FFFu) * bf2f((u32)tin[(ee >> 15) * FDIM + c]);
          }
        }
        for (; j + 4 <= cnt; j += 4) {
#pragma unroll
          for (int u = 0; u < 4; ++u) {
            u32 ee = __shfl(cv, j + u, 64);
            if (act) acc += bf2f(ee & 0x7FFFu) * bf2f((u32)tin[(ee >> 15) * FDIM + c]);
          }
        }
        for (; j < cnt; ++j) {
          u32 ee = __shfl(cv, j, 64);
          if (act) acc += bf2f(ee & 0x7FFFu) * bf2f((u32)tin[(ee >> 15) * FDIM + c]);
        }
        if (!more) break;
        cv = cvn;
        i += 64;
      }
    }
    float dn = dinv[nu];
    float u = fmaxf(acc * dn + x[nu] * rb + bb, 0.f);
    if (do_t) {
      float tf = 0.f;
      int base = c & 48;
#pragma unroll
      for (int f = 0; f < 16; ++f) tf += __shfl(u, base + f, 64) * wreg[f];
      if (act) tout[(size_t)nu * FDIM + c] = f2bf(tf * dn);
    } else {
      float m1v = __shfl(u, lane + 16, 64);
      float m2v = __shfl(u, lane + 32, 64);
      if (lane < NH) hbuf[(size_t)nu * NH + lane] = (u + m1v + m2v) * (1.f / 3.f);
    }
  }
}

// ---------------- BN stats over hbuf [N,16] ---------------------------------
__global__ __launch_bounds__(256) void bn_stats_kernel(
    const float* __restrict__ h, double* __restrict__ stats) {
  __shared__ float ssum[NH], ssq[NH];
  int tid = threadIdx.x;
  if (tid < NH) { ssum[tid] = 0.f; ssq[tid] = 0.f; }
  __syncthreads();
  int n = blockIdx.x * blockDim.x + tid;
  bool valid = n < N_NODES;
  const float4* p = (const float4*)(h + (size_t)(valid ? n : 0) * NH);
  float hv[NH];
#pragma unroll
  for (int q = 0; q < 4; ++q) {
    float4 v = valid ? p[q] : make_float4(0.f, 0.f, 0.f, 0.f);
    hv[q * 4 + 0] = v.x; hv[q * 4 + 1] = v.y; hv[q * 4 + 2] = v.z; hv[q * 4 + 3] = v.w;
  }
#pragma unroll
  for (int f = 0; f < NH; ++f) {
    float s = hv[f], q = hv[f] * hv[f];
    for (int o = 32; o; o >>= 1) { s += __shfl_xor(s, o, 64); q += __shfl_xor(q, o, 64); }
    if ((tid & 63) == 0) { atomicAdd(&ssum[f], s); atomicAdd(&ssq[f], q); }
  }
  __syncthreads();
  if (tid < NH) {
    atomicAdd(&stats[tid], (double)ssum[tid]);
    atomicAdd(&stats[NH + tid], (double)ssq[tid]);
  }
}

__global__ __launch_bounds__(64) void bn_final_kernel(
    const double* __restrict__ stats, const float* __restrict__ g,
    const float* __restrict__ b, float* __restrict__ sc, float* __restrict__ sh) {
  int f = threadIdx.x;
  if (f < NH) {
    double mu = stats[f] / (double)N_NODES;
    double var = stats[NH + f] / (double)N_NODES - mu * mu;
    float scale = g[f] * (float)(1.0 / sqrt(var + (double)BN_EPS));
    sc[f] = scale;
    sh[f] = b[f] - (float)mu * scale;
  }
}

// ---------------- conv2 init: BN-apply + relu + init/root dots --------------
__global__ __launch_bounds__(256) void conv2_init_kernel(
    const float* __restrict__ h, const float* __restrict__ sc, const float* __restrict__ sh,
    const float* __restrict__ dinv,
    const float* __restrict__ w2i, const float* __restrict__ w2r, const float* __restrict__ b2,
    float* __restrict__ P, float* __restrict__ R) {
  int n = blockIdx.x * blockDim.x + threadIdx.x;
  if (n >= N_NODES) return;
  float u[NH];
#pragma unroll
  for (int f = 0; f < NH; ++f) u[f] = fmaxf(h[(size_t)n * NH + f] * sc[f] + sh[f], 0.f);
  float dn = dinv[n];
#pragma unroll
  for (int k = 0; k < 3; ++k) {
    float r = b2[k], o = 0.f;
#pragma unroll
    for (int f = 0; f < NH; ++f) {
      r += u[f] * w2r[k * NH + f];
      o += u[f] * w2i[k * NH + f];
    }
    R[n * 4 + k] = r;
    P[n * 4 + k] = o * dn;
  }
  R[n * 4 + 3] = 0.f;
  P[n * 4 + 3] = 0.f;
}

// ---------------- conv2 propagate: 16-lane groups, packed CSR ---------------
__global__ __launch_bounds__(256) void conv2_prop_kernel(
    const float* __restrict__ in4, float* __restrict__ out4, float* __restrict__ y,
    const u32* __restrict__ csr, const int* __restrict__ offs,
    const float* __restrict__ dinv,
    const float* __restrict__ R, const float* __restrict__ w2,
    int scale_w2, int final_out) {
  int t = blockIdx.x * 256 + threadIdx.x;
  int n = t >> 4, sub = t & 15;
  float m0 = 1.f, m1 = 1.f, m2 = 1.f;
  if (scale_w2) { m0 = w2[0]; m1 = w2[1]; m2 = w2[2]; }
  int s = offs[n], e = offs[n + 1];
  float a0 = 0.f, a1 = 0.f, a2 = 0.f;
  for (int i = s + sub; i < e; i += 16) {
    u32 ee = csr[i];
    float w = bf2f(ee & 0x7FFFu);
    const float4 v = *(const float4*)(in4 + (size_t)(ee >> 15) * 4);
    a0 += w * v.x;
    a1 += w * v.y;
    a2 += w * v.z;
  }
#pragma unroll
  for (int o = 8; o; o >>= 1) {
    a0 += __shfl_xor(a0, o, 64);
    a1 += __shfl_xor(a1, o, 64);
    a2 += __shfl_xor(a2, o, 64);
  }
  if (sub == 0) {
    float dn = dinv[n];
    a0 = a0 * dn * m0 + R[n * 4 + 0];
    a1 = a1 * dn * m1 + R[n * 4 + 1];
    a2 = a2 * dn * m2 + R[n * 4 + 2];
    if (final_out) {
      float sm = (a0 + a1 + a2) * (1.f / 3.f);
      y[n] = 1.f / (1.f + expf(-sm));
    } else {
      out4[n * 4 + 0] = a0 * dn;
      out4[n * 4 + 1] = a1 * dn;
      out4[n * 4 + 2] = a2 * dn;
      out4[n * 4 + 3] = 0.f;
    }
  }
}

extern "C" void kernel_launch(void* const* d_in, const int* in_sizes, int n_in,
                              void* d_out, int out_size, void* d_ws, size_t ws_size,
                              hipStream_t stream) {
  const float* x   = (const float*)d_in[0];
  const int*   ei  = (const int*)d_in[1];
  const float* ea  = (const float*)d_in[2];
  // d_in[3] = batch (unused)
  const float* w1i = (const float*)d_in[4];
  const float* w1  = (const float*)d_in[5];
  const float* w1r = (const float*)d_in[6];
  const float* b1  = (const float*)d_in[7];
  const float* bng = (const float*)d_in[8];
  const float* bnb = (const float*)d_in[9];
  const float* w2i = (const float*)d_in[10];
  const float* w2  = (const float*)d_in[11];
  const float* w2r = (const float*)d_in[12];
  const float* b2  = (const float*)d_in[13];
  float* y = (float*)d_out;

  const int* row = ei;
  const int* col = ei + N_EDGES;

  char* ws = (char*)d_ws;
  size_t off = 0;
  auto alloc = [&](size_t bytes) -> char* {
    char* p = ws + off;
    off += (bytes + 255) & ~(size_t)255;
    return p;
  };
  u32*    gcur   = (u32*)alloc((size_t)NBUCK * 8 * 4);
  int*    offs   = (int*)alloc((size_t)(N_NODES + 1) * 4);
  float*  dinv   = (float*)alloc((size_t)N_NODES * 4);
  u16*    zx     = (u16*)alloc((size_t)N_NODES * 2);
  double* stats  = (double*)alloc(32 * 8);
  float*  bnsc   = (float*)alloc(16 * 4);
  float*  bnsh   = (float*)alloc(16 * 4);
  int2*   bucketed = (int2*)alloc((size_t)NBUCK * CAP * 8);
  u32*    csr    = (u32*)alloc((size_t)N_EDGES * 4);
  u16*    tA     = (u16*)alloc((size_t)N_NODES * FDIM * 2);
  u16*    tB     = (u16*)alloc((size_t)N_NODES * FDIM * 2);
  float*  hbuf   = (float*)alloc((size_t)N_NODES * NH * 4);
  float*  P2     = (float*)alloc((size_t)N_NODES * 4 * 4);
  float*  Q2     = (float*)alloc((size_t)N_NODES * 4 * 4);
  float*  R2     = (float*)alloc((size_t)N_NODES * 4 * 4);
  (void)ws_size; (void)in_sizes; (void)n_in; (void)out_size;

  hipMemsetAsync(gcur, 0, (size_t)NBUCK * 8 * 4, stream);
  hipMemsetAsync(stats, 0, 32 * 8, stream);

  bucket_scatter_kernel<<<NBLK1, 1024, 0, stream>>>(row, col, ea, gcur, bucketed);
  node_offs_kernel<<<NBUCK, 1024, 0, stream>>>(bucketed, gcur, x, offs, dinv, zx);
  csr_fill_kernel<<<NBUCK, 1024, 0, stream>>>(bucketed, gcur, offs, csr);

  const int NPB = 6250;  // N_NODES*16/256 exactly
  // conv1 layer 1 (rank-1 collapse): merged scalar prop + dense epilogue -> tA
  sprop_mid_kernel<<<NPB, 256, 0, stream>>>(csr, offs, zx, dinv, x, w1i, w1r, b1, w1, tA);
  // conv1 layers 2-4: combined 3-stack propagation; 6250 blocks = 4 nodes/wave
  conv1_prop_kernel<<<6250, 256, 0, stream>>>(tA, tB, nullptr, csr, offs, dinv, x, w1r, b1, w1, 1);
  conv1_prop_kernel<<<6250, 256, 0, stream>>>(tB, tA, nullptr, csr, offs, dinv, x, w1r, b1, w1, 1);
  conv1_prop_kernel<<<6250, 256, 0, stream>>>(tA, nullptr, hbuf, csr, offs, dinv, x, w1r, b1, w1, 0);

  bn_stats_kernel<<<(N_NODES + 255) / 256, 256, 0, stream>>>(hbuf, stats);
  bn_final_kernel<<<1, 64, 0, stream>>>(stats, bng, bnb, bnsc, bnsh);
  conv2_init_kernel<<<(N_NODES + 255) / 256, 256, 0, stream>>>(
      hbuf, bnsc, bnsh, dinv, w2i, w2r, b2, P2, R2);

  conv2_prop_kernel<<<NPB, 256, 0, stream>>>(P2, Q2, nullptr, csr, offs, dinv, R2, w2, 0, 0);
  conv2_prop_kernel<<<NPB, 256, 0, stream>>>(Q2, P2, nullptr, csr, offs, dinv, R2, w2, 1, 0);
  conv2_prop_kernel<<<NPB, 256, 0, stream>>>(P2, Q2, nullptr, csr, offs, dinv, R2, w2, 1, 0);
  conv2_prop_kernel<<<NPB, 256, 0, stream>>>(Q2, P2, y, csr, offs, dinv, R2, w2, 1, 1);
}

// Round 4
// 478.899 us; speedup vs baseline: 1.8080x; 1.8080x over previous
//
#include <hip/hip_runtime.h>
#include <math.h>

#define N_NODES 100000
#define N_EDGES 3200000
#define KH 48            // K*H active channels
#define FDIM 64          // padded feature row stride (128 B, line-aligned)
#define NH 16            // H
#define BN_EPS 1e-5f
#define NBUCK 196        // ceil(100000/512) buckets of 512 nodes
#define BSHIFT 9
#define BMASK 511
#define EPB 16384        // edges per block in bucket scatter
#define NBLK1 196        // ceil(N_EDGES/EPB)
#define CAP 18432        // fixed bucket capacity: mean 16327 + 16 sigma
#define FIX 16777216.0f  // 2^24 fixed point for degree sums

typedef unsigned long long u64;
typedef unsigned int u32;
typedef unsigned short u16;

__device__ __forceinline__ u16 f2bf(float f) {
  u32 b = __float_as_uint(f);
  b += 0x7FFFu + ((b >> 16) & 1u);   // RNE
  return (u16)(b >> 16);
}
__device__ __forceinline__ float bf2f(u32 s) {
  return __uint_as_float(s << 16);
}
__device__ __forceinline__ u32 rfl(u32 v) {
  return (u32)__builtin_amdgcn_readfirstlane((int)v);
}

// ---------------- K1: scatter edges into FIXED-CAPACITY buckets -------------
__global__ __launch_bounds__(1024) void bucket_scatter_kernel(
    const int* __restrict__ row, const int* __restrict__ col,
    const float* __restrict__ ea, u32* __restrict__ gcur,
    int2* __restrict__ bucketed) {
  __shared__ u32 bins[NBUCK];
  __shared__ u32 base[NBUCK];
  __shared__ u16 rnk[EPB];
  for (int t = threadIdx.x; t < NBUCK; t += 1024) bins[t] = 0;
  __syncthreads();
  int eb = blockIdx.x * EPB;
  for (int it = 0; it < EPB / 1024; ++it) {
    int i = it * 1024 + threadIdx.x;
    int e = eb + i;
    if (e < N_EDGES) rnk[i] = (u16)atomicAdd(&bins[col[e] >> BSHIFT], 1u);
  }
  __syncthreads();
  for (int t = threadIdx.x; t < NBUCK; t += 1024) {
    u32 c = bins[t];
    if (c) base[t] = (u32)t * CAP + atomicAdd(&gcur[t * 8], c);
  }
  __syncthreads();
  for (int it = 0; it < EPB / 1024; ++it) {
    int i = it * 1024 + threadIdx.x;
    int e = eb + i;
    if (e < N_EDGES) {
      int c = col[e];
      int bkt = c >> BSHIFT, cl = c & BMASK;
      u32 pos = base[bkt] + (u32)rnk[i];
      bucketed[pos] = make_int2((cl << 17) | row[e], __float_as_int(ea[e]));
    }
  }
}

// ---------------- P2a: per-bucket node counts -> offs, dinv, zx -------------
__global__ __launch_bounds__(1024) void node_offs_kernel(
    const int2* __restrict__ bucketed, const u32* __restrict__ gcur,
    const float* __restrict__ x,
    int* __restrict__ offs, float* __restrict__ dinv, u16* __restrict__ zx) {
  __shared__ u32 cnt[512];
  __shared__ u32 degf[512];
  __shared__ u32 red[256];
  __shared__ u32 shmeta[2];   // [0]=bstart, [1]=fill
  int t = threadIdx.x;
  int b = blockIdx.x;
  if (t < 512) { cnt[t] = 0; degf[t] = 0; }
  if (t < 256) red[t] = (t < b) ? gcur[t * 8] : 0;   // NBUCK<256
  __syncthreads();
  for (int d = 128; d; d >>= 1) {
    if (t < d) red[t] += red[t + d];
    __syncthreads();
  }
  if (t == 0) { shmeta[0] = red[0]; shmeta[1] = gcur[b * 8]; }
  __syncthreads();
  u32 bst = shmeta[0], fill = shmeta[1];
  u32 s_pad = (u32)b * CAP;
  for (u32 i = t; i < fill; i += 1024) {
    int2 v = bucketed[s_pad + i];
    int cl = (v.x >> 17) & BMASK;
    atomicAdd(&cnt[cl], 1u);
    atomicAdd(&degf[cl], (u32)(__int_as_float(v.y) * FIX));
  }
  __syncthreads();
  u32 v0 = (t < 512) ? cnt[t] : 0;
  for (int d = 1; d < 512; d <<= 1) {
    u32 u = (t < 512 && t >= d) ? cnt[t - d] : 0;
    __syncthreads();
    if (t < 512) cnt[t] += u;
    __syncthreads();
  }
  int n = b * 512 + t;
  if (t < 512 && n < N_NODES) {
    offs[n] = (int)(bst + cnt[t] - v0);  // exclusive, compact
    float dg = (float)degf[t] * (1.0f / FIX);
    float dv = dg > 0.f ? rsqrtf(fmaxf(dg, 1e-12f)) : 0.f;
    dinv[n] = dv;
    zx[n] = f2bf(x[n] * dv);
  }
  if (b == 0 && t == 0) offs[N_NODES] = N_EDGES;
}

// ---------------- P2b: packed 4B CSR: (src<<15) | bf16(ea) ------------------
__global__ __launch_bounds__(1024) void csr_fill_kernel(
    const int2* __restrict__ bucketed, const u32* __restrict__ gcur,
    const int* __restrict__ offs, u32* __restrict__ csr) {
  __shared__ u32 cur[512];
  __shared__ u32 shfill;
  int t = threadIdx.x;
  int b = blockIdx.x;
  int n = b * 512 + t;
  if (t < 512) cur[t] = (n < N_NODES) ? (u32)offs[n] : 0;
  if (t == 0) shfill = gcur[b * 8];
  __syncthreads();
  u32 fill = shfill;
  u32 s_pad = (u32)b * CAP;
  for (u32 i = t; i < fill; i += 1024) {
    int2 v = bucketed[s_pad + i];
    int cl = (v.x >> 17) & BMASK;
    u32 r = (u32)(v.x & 0x1FFFF);
    u16 w = f2bf(__int_as_float(v.y));   // ea >= 0 -> sign bit 0, w < 0x8000
    u32 pos = atomicAdd(&cur[cl], 1u);
    csr[pos] = (r << 15) | (u32)w;
  }
}

// ---------------- layer-1: scalar prop + epilogue + transform (merged) ------
__global__ __launch_bounds__(256) void sprop_mid_kernel(
    const u32* __restrict__ csr, const int* __restrict__ offs,
    const u16* __restrict__ zx, const float* __restrict__ dinv,
    const float* __restrict__ x,
    const float* __restrict__ w1i, const float* __restrict__ w1r,
    const float* __restrict__ b1, const float* __restrict__ w1,
    u16* __restrict__ tout) {
  int t = blockIdx.x * 256 + threadIdx.x;
  int n = t >> 4, c = t & 15;
  float a = 0.f;
  int s = offs[n], e = offs[n + 1];
  for (int i = s + c; i < e; i += 16) {
    u32 ee = csr[i];
    a += bf2f(ee & 0x7FFFu) * bf2f((u32)zx[ee >> 15]);
  }
#pragma unroll
  for (int o = 8; o; o >>= 1) a += __shfl_xor(a, o, 64);
  float dn = dinv[n];
  float sn = a * dn;
  float xn = x[n];
  int base = (threadIdx.x & 63) & 48;
#pragma unroll
  for (int k = 0; k < 3; ++k) {
    float u = fmaxf(sn * w1i[k * 16 + c] + xn * w1r[k * 16 + c] + b1[k * 16 + c], 0.f);
    float tf = 0.f;
#pragma unroll
    for (int f = 0; f < 16; ++f) tf += __shfl(u, base + f, 64) * w1[k * 256 + f * 16 + c];
    tout[(size_t)n * FDIM + k * 16 + c] = f2bf(tf * dn);
  }
}

// ---------------- conv1 propagate, all 3 stacks combined --------------------
// wave per node, lane = channel, 48 active; rows 128 B line-aligned.
// csr values pulled through the SCALAR path (readfirstlane -> SALU unpack,
// SGPR-based gather addresses): ~3 VALU/edge instead of ~13.
__global__ __launch_bounds__(256) void conv1_prop_kernel(
    const u16* __restrict__ tin, u16* __restrict__ tout, float* __restrict__ hbuf,
    const u32* __restrict__ csr, const int* __restrict__ offs,
    const float* __restrict__ dinv, const float* __restrict__ x,
    const float* __restrict__ w1r, const float* __restrict__ b1,
    const float* __restrict__ w1, int do_t) {
  int lane = threadIdx.x & 63;
  int wid = (blockIdx.x * blockDim.x + threadIdx.x) >> 6;
  int nw = (gridDim.x * blockDim.x) >> 6;
  int c = lane;
  bool act = c < KH;
  float rb = act ? w1r[c] : 0.f;
  float bb = act ? b1[c] : 0.f;
  float wreg[16];
  if (do_t) {
    int k = c >> 4, o = c & 15;
    if (act) {
#pragma unroll
      for (int f = 0; f < 16; ++f) wreg[f] = w1[k * 256 + f * 16 + o];
    } else {
#pragma unroll
      for (int f = 0; f < 16; ++f) wreg[f] = 0.f;
    }
  }
  for (int n = wid; n < N_NODES; n += nw) {
    int nu = __builtin_amdgcn_readfirstlane(n);
    int s = __builtin_amdgcn_readfirstlane(offs[nu]);
    int e = __builtin_amdgcn_readfirstlane(offs[nu + 1]);
    float acc = 0.f;
    int i = s;
    for (; i + 16 <= e; i += 16) {
      u32 e0 = rfl(csr[i]);
      u32 e1 = rfl(csr[i + 1]);
      u32 e2 = rfl(csr[i + 2]);
      u32 e3 = rfl(csr[i + 3]);
      u32 e4 = rfl(csr[i + 4]);
      u32 e5 = rfl(csr[i + 5]);
      u32 e6 = rfl(csr[i + 6]);
      u32 e7 = rfl(csr[i + 7]);
      u32 e8 = rfl(csr[i + 8]);
      u32 e9 = rfl(csr[i + 9]);
      u32 ea0 = rfl(csr[i + 10]);
      u32 eb0 = rfl(csr[i + 11]);
      u32 ec0 = rfl(csr[i + 12]);
      u32 ed0 = rfl(csr[i + 13]);
      u32 ee0 = rfl(csr[i + 14]);
      u32 ef0 = rfl(csr[i + 15]);
      float v0 = bf2f((u32)tin[(e0 >> 15) * FDIM + c]);
      float v1 = bf2f((u32)tin[(e1 >> 15) * FDIM + c]);
      float v2 = bf2f((u32)tin[(e2 >> 15) * FDIM + c]);
      float v3 = bf2f((u32)tin[(e3 >> 15) * FDIM + c]);
      float v4 = bf2f((u32)tin[(e4 >> 15) * FDIM + c]);
      float v5 = bf2f((u32)tin[(e5 >> 15) * FDIM + c]);
      float v6 = bf2f((u32)tin[(e6 >> 15) * FDIM + c]);
      float v7 = bf2f((u32)tin[(e7 >> 15) * FDIM + c]);
      float v8 = bf2f((u32)tin[(e8 >> 15) * FDIM + c]);
      float v9 = bf2f((u32)tin[(e9 >> 15) * FDIM + c]);
      float va = bf2f((u32)tin[(ea0 >> 15) * FDIM + c]);
      float vb = bf2f((u32)tin[(eb0 >> 15) * FDIM + c]);
      float vc = bf2f((u32)tin[(ec0 >> 15) * FDIM + c]);
      float vd = bf2f((u32)tin[(ed0 >> 15) * FDIM + c]);
      float ve = bf2f((u32)tin[(ee0 >> 15) * FDIM + c]);
      float vf = bf2f((u32)tin[(ef0 >> 15) * FDIM + c]);
      acc += bf2f(e0 & 0x7FFFu) * v0 + bf2f(e1 & 0x7FFFu) * v1 +
             bf2f(e2 & 0x7FFFu) * v2 + bf2f(e3 & 0x7FFFu) * v3 +
             bf2f(e4 & 0x7FFFu) * v4 + bf2f(e5 & 0x7FFFu) * v5 +
             bf2f(e6 & 0x7FFFu) * v6 + bf2f(e7 & 0x7FFFu) * v7 +
             bf2f(e8 & 0x7FFFu) * v8 + bf2f(e9 & 0x7FFFu) * v9 +
             bf2f(ea0 & 0x7FFFu) * va + bf2f(eb0 & 0x7FFFu) * vb +
             bf2f(ec0 & 0x7FFFu) * vc + bf2f(ed0 & 0x7FFFu) * vd +
             bf2f(ee0 & 0x7FFFu) * ve + bf2f(ef0 & 0x7FFFu) * vf;
    }
    for (; i + 4 <= e; i += 4) {
      u32 e0 = rfl(csr[i]);
      u32 e1 = rfl(csr[i + 1]);
      u32 e2 = rfl(csr[i + 2]);
      u32 e3 = rfl(csr[i + 3]);
      float v0 = bf2f((u32)tin[(e0 >> 15) * FDIM + c]);
      float v1 = bf2f((u32)tin[(e1 >> 15) * FDIM + c]);
      float v2 = bf2f((u32)tin[(e2 >> 15) * FDIM + c]);
      float v3 = bf2f((u32)tin[(e3 >> 15) * FDIM + c]);
      acc += bf2f(e0 & 0x7FFFu) * v0 + bf2f(e1 & 0x7FFFu) * v1 +
             bf2f(e2 & 0x7FFFu) * v2 + bf2f(e3 & 0x7FFFu) * v3;
    }
    for (; i < e; ++i) {
      u32 ee = rfl(csr[i]);
      acc += bf2f(ee & 0x7FFFu) * bf2f((u32)tin[(ee >> 15) * FDIM + c]);
    }
    float dn = dinv[nu];
    float u = fmaxf(acc * dn + x[nu] * rb + bb, 0.f);
    if (do_t) {
      float tf = 0.f;
      int base = c & 48;
#pragma unroll
      for (int f = 0; f < 16; ++f) tf += __shfl(u, base + f, 64) * wreg[f];
      if (act) tout[(size_t)nu * FDIM + c] = f2bf(tf * dn);
    } else {
      float m1v = __shfl(u, lane + 16, 64);
      float m2v = __shfl(u, lane + 32, 64);
      if (lane < NH) hbuf[(size_t)nu * NH + lane] = (u + m1v + m2v) * (1.f / 3.f);
    }
  }
}

// ---------------- BN stats over hbuf [N,16] ---------------------------------
__global__ __launch_bounds__(256) void bn_stats_kernel(
    const float* __restrict__ h, double* __restrict__ stats) {
  __shared__ float ssum[NH], ssq[NH];
  int tid = threadIdx.x;
  if (tid < NH) { ssum[tid] = 0.f; ssq[tid] = 0.f; }
  __syncthreads();
  int n = blockIdx.x * blockDim.x + tid;
  bool valid = n < N_NODES;
  const float4* p = (const float4*)(h + (size_t)(valid ? n : 0) * NH);
  float hv[NH];
#pragma unroll
  for (int q = 0; q < 4; ++q) {
    float4 v = valid ? p[q] : make_float4(0.f, 0.f, 0.f, 0.f);
    hv[q * 4 + 0] = v.x; hv[q * 4 + 1] = v.y; hv[q * 4 + 2] = v.z; hv[q * 4 + 3] = v.w;
  }
#pragma unroll
  for (int f = 0; f < NH; ++f) {
    float s = hv[f], q = hv[f] * hv[f];
    for (int o = 32; o; o >>= 1) { s += __shfl_xor(s, o, 64); q += __shfl_xor(q, o, 64); }
    if ((tid & 63) == 0) { atomicAdd(&ssum[f], s); atomicAdd(&ssq[f], q); }
  }
  __syncthreads();
  if (tid < NH) {
    atomicAdd(&stats[tid], (double)ssum[tid]);
    atomicAdd(&stats[NH + tid], (double)ssq[tid]);
  }
}

__global__ __launch_bounds__(64) void bn_final_kernel(
    const double* __restrict__ stats, const float* __restrict__ g,
    const float* __restrict__ b, float* __restrict__ sc, float* __restrict__ sh) {
  int f = threadIdx.x;
  if (f < NH) {
    double mu = stats[f] / (double)N_NODES;
    double var = stats[NH + f] / (double)N_NODES - mu * mu;
    float scale = g[f] * (float)(1.0 / sqrt(var + (double)BN_EPS));
    sc[f] = scale;
    sh[f] = b[f] - (float)mu * scale;
  }
}

// ---------------- conv2 init: BN-apply + relu + init/root dots --------------
__global__ __launch_bounds__(256) void conv2_init_kernel(
    const float* __restrict__ h, const float* __restrict__ sc, const float* __restrict__ sh,
    const float* __restrict__ dinv,
    const float* __restrict__ w2i, const float* __restrict__ w2r, const float* __restrict__ b2,
    float* __restrict__ P, float* __restrict__ R) {
  int n = blockIdx.x * blockDim.x + threadIdx.x;
  if (n >= N_NODES) return;
  float u[NH];
#pragma unroll
  for (int f = 0; f < NH; ++f) u[f] = fmaxf(h[(size_t)n * NH + f] * sc[f] + sh[f], 0.f);
  float dn = dinv[n];
#pragma unroll
  for (int k = 0; k < 3; ++k) {
    float r = b2[k], o = 0.f;
#pragma unroll
    for (int f = 0; f < NH; ++f) {
      r += u[f] * w2r[k * NH + f];
      o += u[f] * w2i[k * NH + f];
    }
    R[n * 4 + k] = r;
    P[n * 4 + k] = o * dn;
  }
  R[n * 4 + 3] = 0.f;
  P[n * 4 + 3] = 0.f;
}

// ---------------- conv2 propagate: 16-lane groups, packed CSR ---------------
__global__ __launch_bounds__(256) void conv2_prop_kernel(
    const float* __restrict__ in4, float* __restrict__ out4, float* __restrict__ y,
    const u32* __restrict__ csr, const int* __restrict__ offs,
    const float* __restrict__ dinv,
    const float* __restrict__ R, const float* __restrict__ w2,
    int scale_w2, int final_out) {
  int t = blockIdx.x * 256 + threadIdx.x;
  int n = t >> 4, sub = t & 15;
  float m0 = 1.f, m1 = 1.f, m2 = 1.f;
  if (scale_w2) { m0 = w2[0]; m1 = w2[1]; m2 = w2[2]; }
  int s = offs[n], e = offs[n + 1];
  float a0 = 0.f, a1 = 0.f, a2 = 0.f;
  for (int i = s + sub; i < e; i += 16) {
    u32 ee = csr[i];
    float w = bf2f(ee & 0x7FFFu);
    const float4 v = *(const float4*)(in4 + (size_t)(ee >> 15) * 4);
    a0 += w * v.x;
    a1 += w * v.y;
    a2 += w * v.z;
  }
#pragma unroll
  for (int o = 8; o; o >>= 1) {
    a0 += __shfl_xor(a0, o, 64);
    a1 += __shfl_xor(a1, o, 64);
    a2 += __shfl_xor(a2, o, 64);
  }
  if (sub == 0) {
    float dn = dinv[n];
    a0 = a0 * dn * m0 + R[n * 4 + 0];
    a1 = a1 * dn * m1 + R[n * 4 + 1];
    a2 = a2 * dn * m2 + R[n * 4 + 2];
    if (final_out) {
      float sm = (a0 + a1 + a2) * (1.f / 3.f);
      y[n] = 1.f / (1.f + expf(-sm));
    } else {
      out4[n * 4 + 0] = a0 * dn;
      out4[n * 4 + 1] = a1 * dn;
      out4[n * 4 + 2] = a2 * dn;
      out4[n * 4 + 3] = 0.f;
    }
  }
}

extern "C" void kernel_launch(void* const* d_in, const int* in_sizes, int n_in,
                              void* d_out, int out_size, void* d_ws, size_t ws_size,
                              hipStream_t stream) {
  const float* x   = (const float*)d_in[0];
  const int*   ei  = (const int*)d_in[1];
  const float* ea  = (const float*)d_in[2];
  // d_in[3] = batch (unused)
  const float* w1i = (const float*)d_in[4];
  const float* w1  = (const float*)d_in[5];
  const float* w1r = (const float*)d_in[6];
  const float* b1  = (const float*)d_in[7];
  const float* bng = (const float*)d_in[8];
  const float* bnb = (const float*)d_in[9];
  const float* w2i = (const float*)d_in[10];
  const float* w2  = (const float*)d_in[11];
  const float* w2r = (const float*)d_in[12];
  const float* b2  = (const float*)d_in[13];
  float* y = (float*)d_out;

  const int* row = ei;
  const int* col = ei + N_EDGES;

  char* ws = (char*)d_ws;
  size_t off = 0;
  auto alloc = [&](size_t bytes) -> char* {
    char* p = ws + off;
    off += (bytes + 255) & ~(size_t)255;
    return p;
  };
  u32*    gcur   = (u32*)alloc((size_t)NBUCK * 8 * 4);
  int*    offs   = (int*)alloc((size_t)(N_NODES + 1) * 4);
  float*  dinv   = (float*)alloc((size_t)N_NODES * 4);
  u16*    zx     = (u16*)alloc((size_t)N_NODES * 2);
  double* stats  = (double*)alloc(32 * 8);
  float*  bnsc   = (float*)alloc(16 * 4);
  float*  bnsh   = (float*)alloc(16 * 4);
  int2*   bucketed = (int2*)alloc((size_t)NBUCK * CAP * 8);
  u32*    csr    = (u32*)alloc((size_t)N_EDGES * 4);
  u16*    tA     = (u16*)alloc((size_t)N_NODES * FDIM * 2);
  u16*    tB     = (u16*)alloc((size_t)N_NODES * FDIM * 2);
  float*  hbuf   = (float*)alloc((size_t)N_NODES * NH * 4);
  float*  P2     = (float*)alloc((size_t)N_NODES * 4 * 4);
  float*  Q2     = (float*)alloc((size_t)N_NODES * 4 * 4);
  float*  R2     = (float*)alloc((size_t)N_NODES * 4 * 4);
  (void)ws_size; (void)in_sizes; (void)n_in; (void)out_size;

  hipMemsetAsync(gcur, 0, (size_t)NBUCK * 8 * 4, stream);
  hipMemsetAsync(stats, 0, 32 * 8, stream);

  bucket_scatter_kernel<<<NBLK1, 1024, 0, stream>>>(row, col, ea, gcur, bucketed);
  node_offs_kernel<<<NBUCK, 1024, 0, stream>>>(bucketed, gcur, x, offs, dinv, zx);
  csr_fill_kernel<<<NBUCK, 1024, 0, stream>>>(bucketed, gcur, offs, csr);

  const int NPB = 6250;  // N_NODES*16/256 exactly
  // conv1 layer 1 (rank-1 collapse): merged scalar prop + dense epilogue -> tA
  sprop_mid_kernel<<<NPB, 256, 0, stream>>>(csr, offs, zx, dinv, x, w1i, w1r, b1, w1, tA);
  // conv1 layers 2-4: combined 3-stack propagation; 6250 blocks = 4 nodes/wave
  conv1_prop_kernel<<<6250, 256, 0, stream>>>(tA, tB, nullptr, csr, offs, dinv, x, w1r, b1, w1, 1);
  conv1_prop_kernel<<<6250, 256, 0, stream>>>(tB, tA, nullptr, csr, offs, dinv, x, w1r, b1, w1, 1);
  conv1_prop_kernel<<<6250, 256, 0, stream>>>(tA, nullptr, hbuf, csr, offs, dinv, x, w1r, b1, w1, 0);

  bn_stats_kernel<<<(N_NODES + 255) / 256, 256, 0, stream>>>(hbuf, stats);
  bn_final_kernel<<<1, 64, 0, stream>>>(stats, bng, bnb, bnsc, bnsh);
  conv2_init_kernel<<<(N_NODES + 255) / 256, 256, 0, stream>>>(
      hbuf, bnsc, bnsh, dinv, w2i, w2r, b2, P2, R2);

  conv2_prop_kernel<<<NPB, 256, 0, stream>>>(P2, Q2, nullptr, csr, offs, dinv, R2, w2, 0, 0);
  conv2_prop_kernel<<<NPB, 256, 0, stream>>>(Q2, P2, nullptr, csr, offs, dinv, R2, w2, 1, 0);
  conv2_prop_kernel<<<NPB, 256, 0, stream>>>(P2, Q2, nullptr, csr, offs, dinv, R2, w2, 1, 0);
  conv2_prop_kernel<<<NPB, 256, 0, stream>>>(Q2, P2, y, csr, offs, dinv, R2, w2, 1, 1);
}

// Round 5
// 469.620 us; speedup vs baseline: 1.8437x; 1.0198x over previous
//
#include <hip/hip_runtime.h>
#include <math.h>

#define N_NODES 100000
#define N_EDGES 3200000
#define KH 48            // K*H active channels
#define FDIM 64          // padded feature row stride (128 B, line-aligned)
#define NH 16            // H
#define BN_EPS 1e-5f
#define NBUCK 196        // ceil(100000/512) buckets of 512 nodes
#define BSHIFT 9
#define BMASK 511
#define EPB 16384        // edges per block in bucket scatter
#define NBLK1 196        // ceil(N_EDGES/EPB)
#define CAP 18432        // fixed bucket capacity: mean 16327 + 16 sigma
#define FIX 16777216.0f  // 2^24 fixed point for degree sums

typedef unsigned long long u64;
typedef unsigned int u32;
typedef unsigned short u16;

__device__ __forceinline__ u16 f2bf(float f) {
  u32 b = __float_as_uint(f);
  b += 0x7FFFu + ((b >> 16) & 1u);   // RNE
  return (u16)(b >> 16);
}
__device__ __forceinline__ float bf2f(u32 s) {
  return __uint_as_float(s << 16);
}
__device__ __forceinline__ u32 rfl(u32 v) {
  return (u32)__builtin_amdgcn_readfirstlane((int)v);
}

// ---------------- K1: scatter edges into FIXED-CAPACITY buckets -------------
__global__ __launch_bounds__(1024) void bucket_scatter_kernel(
    const int* __restrict__ row, const int* __restrict__ col,
    const float* __restrict__ ea, u32* __restrict__ gcur,
    int2* __restrict__ bucketed) {
  __shared__ u32 bins[NBUCK];
  __shared__ u32 base[NBUCK];
  __shared__ u16 rnk[EPB];
  for (int t = threadIdx.x; t < NBUCK; t += 1024) bins[t] = 0;
  __syncthreads();
  int eb = blockIdx.x * EPB;
  for (int it = 0; it < EPB / 1024; ++it) {
    int i = it * 1024 + threadIdx.x;
    int e = eb + i;
    if (e < N_EDGES) rnk[i] = (u16)atomicAdd(&bins[col[e] >> BSHIFT], 1u);
  }
  __syncthreads();
  for (int t = threadIdx.x; t < NBUCK; t += 1024) {
    u32 c = bins[t];
    if (c) base[t] = (u32)t * CAP + atomicAdd(&gcur[t * 8], c);
  }
  __syncthreads();
  for (int it = 0; it < EPB / 1024; ++it) {
    int i = it * 1024 + threadIdx.x;
    int e = eb + i;
    if (e < N_EDGES) {
      int c = col[e];
      int bkt = c >> BSHIFT, cl = c & BMASK;
      u32 pos = base[bkt] + (u32)rnk[i];
      bucketed[pos] = make_int2((cl << 17) | row[e], __float_as_int(ea[e]));
    }
  }
}

// ---------------- P2: FUSED per-bucket offs/dinv/zx + csr fill --------------
// Phase 1: count + degree (scan bucketed), compute compact offs, dinv, zx.
// Phase 2: re-scan bucketed (L2-warm) and place packed csr entries.
__global__ __launch_bounds__(1024) void node_offs_csr_kernel(
    const int2* __restrict__ bucketed, const u32* __restrict__ gcur,
    const float* __restrict__ x,
    int* __restrict__ offs, float* __restrict__ dinv, u16* __restrict__ zx,
    u32* __restrict__ csr) {
  __shared__ u32 cnt[512];
  __shared__ u32 degf[512];
  __shared__ u32 cur[512];
  __shared__ u32 red[256];
  __shared__ u32 shmeta[2];   // [0]=bstart, [1]=fill
  int t = threadIdx.x;
  int b = blockIdx.x;
  if (t < 512) { cnt[t] = 0; degf[t] = 0; }
  if (t < 256) red[t] = (t < b) ? gcur[t * 8] : 0;   // NBUCK<256
  __syncthreads();
  for (int d = 128; d; d >>= 1) {
    if (t < d) red[t] += red[t + d];
    __syncthreads();
  }
  if (t == 0) { shmeta[0] = red[0]; shmeta[1] = gcur[b * 8]; }
  __syncthreads();
  u32 bst = shmeta[0], fill = shmeta[1];
  u32 s_pad = (u32)b * CAP;
  for (u32 i = t; i < fill; i += 1024) {
    int2 v = bucketed[s_pad + i];
    int cl = (v.x >> 17) & BMASK;
    atomicAdd(&cnt[cl], 1u);
    atomicAdd(&degf[cl], (u32)(__int_as_float(v.y) * FIX));
  }
  __syncthreads();
  u32 v0 = (t < 512) ? cnt[t] : 0;
  for (int d = 1; d < 512; d <<= 1) {
    u32 u = (t < 512 && t >= d) ? cnt[t - d] : 0;
    __syncthreads();
    if (t < 512) cnt[t] += u;
    __syncthreads();
  }
  int n = b * 512 + t;
  if (t < 512) {
    if (n < N_NODES) {
      u32 off0 = bst + cnt[t] - v0;   // exclusive, compact
      offs[n] = (int)off0;
      cur[t] = off0;
      float dg = (float)degf[t] * (1.0f / FIX);
      float dv = dg > 0.f ? rsqrtf(fmaxf(dg, 1e-12f)) : 0.f;
      dinv[n] = dv;
      zx[n] = f2bf(x[n] * dv);
    } else {
      cur[t] = 0;
    }
  }
  if (b == 0 && t == 0) offs[N_NODES] = N_EDGES;
  __syncthreads();
  for (u32 i = t; i < fill; i += 1024) {
    int2 v = bucketed[s_pad + i];
    int cl = (v.x >> 17) & BMASK;
    u32 r = (u32)(v.x & 0x1FFFF);
    u16 w = f2bf(__int_as_float(v.y));   // ea >= 0 -> sign bit 0, w < 0x8000
    u32 pos = atomicAdd(&cur[cl], 1u);
    csr[pos] = (r << 15) | (u32)w;
  }
}

// ---------------- layer-1: scalar prop + epilogue + transform (merged) ------
__global__ __launch_bounds__(256) void sprop_mid_kernel(
    const u32* __restrict__ csr, const int* __restrict__ offs,
    const u16* __restrict__ zx, const float* __restrict__ dinv,
    const float* __restrict__ x,
    const float* __restrict__ w1i, const float* __restrict__ w1r,
    const float* __restrict__ b1, const float* __restrict__ w1,
    u16* __restrict__ tout) {
  int t = blockIdx.x * 256 + threadIdx.x;
  int n = t >> 4, c = t & 15;
  float a = 0.f;
  int s = offs[n], e = offs[n + 1];
  for (int i = s + c; i < e; i += 16) {
    u32 ee = csr[i];
    a += bf2f(ee & 0x7FFFu) * bf2f((u32)zx[ee >> 15]);
  }
#pragma unroll
  for (int o = 8; o; o >>= 1) a += __shfl_xor(a, o, 64);
  float dn = dinv[n];
  float sn = a * dn;
  float xn = x[n];
  int base = (threadIdx.x & 63) & 48;
#pragma unroll
  for (int k = 0; k < 3; ++k) {
    float u = fmaxf(sn * w1i[k * 16 + c] + xn * w1r[k * 16 + c] + b1[k * 16 + c], 0.f);
    float tf = 0.f;
#pragma unroll
    for (int f = 0; f < 16; ++f) tf += __shfl(u, base + f, 64) * w1[k * 256 + f * 16 + c];
    tout[(size_t)n * FDIM + k * 16 + c] = f2bf(tf * dn);
  }
}

// ---------------- conv1 propagate, all 3 stacks combined --------------------
// wave per node, lane = channel, 48 active; rows 128 B line-aligned.
// Scalar-path csr (readfirstlane -> s_load) with SOFTWARE-PIPELINED 16-edge
// blocks: block t+1's csr loads issue before block t's gathers, hiding the
// csr (lgkm) latency under the gather (vmcnt) leg.
#define DECL16(p) u32 p##0, p##1, p##2, p##3, p##4, p##5, p##6, p##7, \
                      p##8, p##9, p##10, p##11, p##12, p##13, p##14, p##15
#define LOAD16(p, base) \
  p##0 = rfl(csr[(base)]);      p##1 = rfl(csr[(base) + 1]);  \
  p##2 = rfl(csr[(base) + 2]);  p##3 = rfl(csr[(base) + 3]);  \
  p##4 = rfl(csr[(base) + 4]);  p##5 = rfl(csr[(base) + 5]);  \
  p##6 = rfl(csr[(base) + 6]);  p##7 = rfl(csr[(base) + 7]);  \
  p##8 = rfl(csr[(base) + 8]);  p##9 = rfl(csr[(base) + 9]);  \
  p##10 = rfl(csr[(base) + 10]); p##11 = rfl(csr[(base) + 11]); \
  p##12 = rfl(csr[(base) + 12]); p##13 = rfl(csr[(base) + 13]); \
  p##14 = rfl(csr[(base) + 14]); p##15 = rfl(csr[(base) + 15])
#define COPY16(d, s2) \
  d##0 = s2##0; d##1 = s2##1; d##2 = s2##2; d##3 = s2##3; \
  d##4 = s2##4; d##5 = s2##5; d##6 = s2##6; d##7 = s2##7; \
  d##8 = s2##8; d##9 = s2##9; d##10 = s2##10; d##11 = s2##11; \
  d##12 = s2##12; d##13 = s2##13; d##14 = s2##14; d##15 = s2##15
#define PROC16(p) do { \
  float v0 = bf2f((u32)tin[(p##0 >> 15) * FDIM + c]); \
  float v1 = bf2f((u32)tin[(p##1 >> 15) * FDIM + c]); \
  float v2 = bf2f((u32)tin[(p##2 >> 15) * FDIM + c]); \
  float v3 = bf2f((u32)tin[(p##3 >> 15) * FDIM + c]); \
  float v4 = bf2f((u32)tin[(p##4 >> 15) * FDIM + c]); \
  float v5 = bf2f((u32)tin[(p##5 >> 15) * FDIM + c]); \
  float v6 = bf2f((u32)tin[(p##6 >> 15) * FDIM + c]); \
  float v7 = bf2f((u32)tin[(p##7 >> 15) * FDIM + c]); \
  float v8 = bf2f((u32)tin[(p##8 >> 15) * FDIM + c]); \
  float v9 = bf2f((u32)tin[(p##9 >> 15) * FDIM + c]); \
  float va = bf2f((u32)tin[(p##10 >> 15) * FDIM + c]); \
  float vb = bf2f((u32)tin[(p##11 >> 15) * FDIM + c]); \
  float vc = bf2f((u32)tin[(p##12 >> 15) * FDIM + c]); \
  float vd = bf2f((u32)tin[(p##13 >> 15) * FDIM + c]); \
  float ve = bf2f((u32)tin[(p##14 >> 15) * FDIM + c]); \
  float vf = bf2f((u32)tin[(p##15 >> 15) * FDIM + c]); \
  acc += bf2f(p##0 & 0x7FFFu) * v0 + bf2f(p##1 & 0x7FFFu) * v1 + \
         bf2f(p##2 & 0x7FFFu) * v2 + bf2f(p##3 & 0x7FFFu) * v3 + \
         bf2f(p##4 & 0x7FFFu) * v4 + bf2f(p##5 & 0x7FFFu) * v5 + \
         bf2f(p##6 & 0x7FFFu) * v6 + bf2f(p##7 & 0x7FFFu) * v7 + \
         bf2f(p##8 & 0x7FFFu) * v8 + bf2f(p##9 & 0x7FFFu) * v9 + \
         bf2f(p##10 & 0x7FFFu) * va + bf2f(p##11 & 0x7FFFu) * vb + \
         bf2f(p##12 & 0x7FFFu) * vc + bf2f(p##13 & 0x7FFFu) * vd + \
         bf2f(p##14 & 0x7FFFu) * ve + bf2f(p##15 & 0x7FFFu) * vf; \
} while (0)

__global__ __launch_bounds__(256) void conv1_prop_kernel(
    const u16* __restrict__ tin, u16* __restrict__ tout, float* __restrict__ hbuf,
    const u32* __restrict__ csr, const int* __restrict__ offs,
    const float* __restrict__ dinv, const float* __restrict__ x,
    const float* __restrict__ w1r, const float* __restrict__ b1,
    const float* __restrict__ w1, int do_t) {
  int lane = threadIdx.x & 63;
  int wid = (blockIdx.x * blockDim.x + threadIdx.x) >> 6;
  int nw = (gridDim.x * blockDim.x) >> 6;
  int c = lane;
  bool act = c < KH;
  float rb = act ? w1r[c] : 0.f;
  float bb = act ? b1[c] : 0.f;
  float wreg[16];
  if (do_t) {
    int k = c >> 4, o = c & 15;
    if (act) {
#pragma unroll
      for (int f = 0; f < 16; ++f) wreg[f] = w1[k * 256 + f * 16 + o];
    } else {
#pragma unroll
      for (int f = 0; f < 16; ++f) wreg[f] = 0.f;
    }
  }
  for (int n = wid; n < N_NODES; n += nw) {
    int nu = __builtin_amdgcn_readfirstlane(n);
    int s = __builtin_amdgcn_readfirstlane(offs[nu]);
    int e = __builtin_amdgcn_readfirstlane(offs[nu + 1]);
    float acc = 0.f;
    int i = s;
    int nblk = (e - s) >> 4;
    if (nblk > 0) {
      DECL16(a);
      DECL16(b);
      LOAD16(a, i);
      for (int blk = 1; blk < nblk; ++blk) {
        int j = i + 16;
        LOAD16(b, j);          // prefetch next block (lgkm, overlaps gathers)
        PROC16(a);             // gathers + FMAs for current block
        COPY16(a, b);
        i = j;
      }
      PROC16(a);               // drain final block
      i += 16;
    }
    for (; i + 4 <= e; i += 4) {
      u32 e0 = rfl(csr[i]);
      u32 e1 = rfl(csr[i + 1]);
      u32 e2 = rfl(csr[i + 2]);
      u32 e3 = rfl(csr[i + 3]);
      float v0 = bf2f((u32)tin[(e0 >> 15) * FDIM + c]);
      float v1 = bf2f((u32)tin[(e1 >> 15) * FDIM + c]);
      float v2 = bf2f((u32)tin[(e2 >> 15) * FDIM + c]);
      float v3 = bf2f((u32)tin[(e3 >> 15) * FDIM + c]);
      acc += bf2f(e0 & 0x7FFFu) * v0 + bf2f(e1 & 0x7FFFu) * v1 +
             bf2f(e2 & 0x7FFFu) * v2 + bf2f(e3 & 0x7FFFu) * v3;
    }
    for (; i < e; ++i) {
      u32 ee = rfl(csr[i]);
      acc += bf2f(ee & 0x7FFFu) * bf2f((u32)tin[(ee >> 15) * FDIM + c]);
    }
    float dn = dinv[nu];
    float u = fmaxf(acc * dn + x[nu] * rb + bb, 0.f);
    if (do_t) {
      float tf = 0.f;
      int base = c & 48;
#pragma unroll
      for (int f = 0; f < 16; ++f) tf += __shfl(u, base + f, 64) * wreg[f];
      if (act) tout[(size_t)nu * FDIM + c] = f2bf(tf * dn);
    } else {
      float m1v = __shfl(u, lane + 16, 64);
      float m2v = __shfl(u, lane + 32, 64);
      if (lane < NH) hbuf[(size_t)nu * NH + lane] = (u + m1v + m2v) * (1.f / 3.f);
    }
  }
}

// ---------------- BN stats over hbuf [N,16] ---------------------------------
__global__ __launch_bounds__(256) void bn_stats_kernel(
    const float* __restrict__ h, double* __restrict__ stats) {
  __shared__ float ssum[NH], ssq[NH];
  int tid = threadIdx.x;
  if (tid < NH) { ssum[tid] = 0.f; ssq[tid] = 0.f; }
  __syncthreads();
  int n = blockIdx.x * blockDim.x + tid;
  bool valid = n < N_NODES;
  const float4* p = (const float4*)(h + (size_t)(valid ? n : 0) * NH);
  float hv[NH];
#pragma unroll
  for (int q = 0; q < 4; ++q) {
    float4 v = valid ? p[q] : make_float4(0.f, 0.f, 0.f, 0.f);
    hv[q * 4 + 0] = v.x; hv[q * 4 + 1] = v.y; hv[q * 4 + 2] = v.z; hv[q * 4 + 3] = v.w;
  }
#pragma unroll
  for (int f = 0; f < NH; ++f) {
    float s = hv[f], q = hv[f] * hv[f];
    for (int o = 32; o; o >>= 1) { s += __shfl_xor(s, o, 64); q += __shfl_xor(q, o, 64); }
    if ((tid & 63) == 0) { atomicAdd(&ssum[f], s); atomicAdd(&ssq[f], q); }
  }
  __syncthreads();
  if (tid < NH) {
    atomicAdd(&stats[tid], (double)ssum[tid]);
    atomicAdd(&stats[NH + tid], (double)ssq[tid]);
  }
}

__global__ __launch_bounds__(64) void bn_final_kernel(
    const double* __restrict__ stats, const float* __restrict__ g,
    const float* __restrict__ b, float* __restrict__ sc, float* __restrict__ sh) {
  int f = threadIdx.x;
  if (f < NH) {
    double mu = stats[f] / (double)N_NODES;
    double var = stats[NH + f] / (double)N_NODES - mu * mu;
    float scale = g[f] * (float)(1.0 / sqrt(var + (double)BN_EPS));
    sc[f] = scale;
    sh[f] = b[f] - (float)mu * scale;
  }
}

// ---------------- conv2 init: BN-apply + relu + init/root dots --------------
__global__ __launch_bounds__(256) void conv2_init_kernel(
    const float* __restrict__ h, const float* __restrict__ sc, const float* __restrict__ sh,
    const float* __restrict__ dinv,
    const float* __restrict__ w2i, const float* __restrict__ w2r, const float* __restrict__ b2,
    float* __restrict__ P, float* __restrict__ R) {
  int n = blockIdx.x * blockDim.x + threadIdx.x;
  if (n >= N_NODES) return;
  float u[NH];
#pragma unroll
  for (int f = 0; f < NH; ++f) u[f] = fmaxf(h[(size_t)n * NH + f] * sc[f] + sh[f], 0.f);
  float dn = dinv[n];
#pragma unroll
  for (int k = 0; k < 3; ++k) {
    float r = b2[k], o = 0.f;
#pragma unroll
    for (int f = 0; f < NH; ++f) {
      r += u[f] * w2r[k * NH + f];
      o += u[f] * w2i[k * NH + f];
    }
    R[n * 4 + k] = r;
    P[n * 4 + k] = o * dn;
  }
  R[n * 4 + 3] = 0.f;
  P[n * 4 + 3] = 0.f;
}

// ---------------- conv2 propagate: 16-lane groups, packed CSR ---------------
__global__ __launch_bounds__(256) void conv2_prop_kernel(
    const float* __restrict__ in4, float* __restrict__ out4, float* __restrict__ y,
    const u32* __restrict__ csr, const int* __restrict__ offs,
    const float* __restrict__ dinv,
    const float* __restrict__ R, const float* __restrict__ w2,
    int scale_w2, int final_out) {
  int t = blockIdx.x * 256 + threadIdx.x;
  int n = t >> 4, sub = t & 15;
  float m0 = 1.f, m1 = 1.f, m2 = 1.f;
  if (scale_w2) { m0 = w2[0]; m1 = w2[1]; m2 = w2[2]; }
  int s = offs[n], e = offs[n + 1];
  float a0 = 0.f, a1 = 0.f, a2 = 0.f;
  for (int i = s + sub; i < e; i += 16) {
    u32 ee = csr[i];
    float w = bf2f(ee & 0x7FFFu);
    const float4 v = *(const float4*)(in4 + (size_t)(ee >> 15) * 4);
    a0 += w * v.x;
    a1 += w * v.y;
    a2 += w * v.z;
  }
#pragma unroll
  for (int o = 8; o; o >>= 1) {
    a0 += __shfl_xor(a0, o, 64);
    a1 += __shfl_xor(a1, o, 64);
    a2 += __shfl_xor(a2, o, 64);
  }
  if (sub == 0) {
    float dn = dinv[n];
    a0 = a0 * dn * m0 + R[n * 4 + 0];
    a1 = a1 * dn * m1 + R[n * 4 + 1];
    a2 = a2 * dn * m2 + R[n * 4 + 2];
    if (final_out) {
      float sm = (a0 + a1 + a2) * (1.f / 3.f);
      y[n] = 1.f / (1.f + expf(-sm));
    } else {
      out4[n * 4 + 0] = a0 * dn;
      out4[n * 4 + 1] = a1 * dn;
      out4[n * 4 + 2] = a2 * dn;
      out4[n * 4 + 3] = 0.f;
    }
  }
}

extern "C" void kernel_launch(void* const* d_in, const int* in_sizes, int n_in,
                              void* d_out, int out_size, void* d_ws, size_t ws_size,
                              hipStream_t stream) {
  const float* x   = (const float*)d_in[0];
  const int*   ei  = (const int*)d_in[1];
  const float* ea  = (const float*)d_in[2];
  // d_in[3] = batch (unused)
  const float* w1i = (const float*)d_in[4];
  const float* w1  = (const float*)d_in[5];
  const float* w1r = (const float*)d_in[6];
  const float* b1  = (const float*)d_in[7];
  const float* bng = (const float*)d_in[8];
  const float* bnb = (const float*)d_in[9];
  const float* w2i = (const float*)d_in[10];
  const float* w2  = (const float*)d_in[11];
  const float* w2r = (const float*)d_in[12];
  const float* b2  = (const float*)d_in[13];
  float* y = (float*)d_out;

  const int* row = ei;
  const int* col = ei + N_EDGES;

  char* ws = (char*)d_ws;
  size_t off = 0;
  auto alloc = [&](size_t bytes) -> char* {
    char* p = ws + off;
    off += (bytes + 255) & ~(size_t)255;
    return p;
  };
  u32*    gcur   = (u32*)alloc((size_t)NBUCK * 8 * 4);
  int*    offs   = (int*)alloc((size_t)(N_NODES + 1) * 4);
  float*  dinv   = (float*)alloc((size_t)N_NODES * 4);
  u16*    zx     = (u16*)alloc((size_t)N_NODES * 2);
  double* stats  = (double*)alloc(32 * 8);
  float*  bnsc   = (float*)alloc(16 * 4);
  float*  bnsh   = (float*)alloc(16 * 4);
  int2*   bucketed = (int2*)alloc((size_t)NBUCK * CAP * 8);
  u32*    csr    = (u32*)alloc((size_t)N_EDGES * 4);
  u16*    tA     = (u16*)alloc((size_t)N_NODES * FDIM * 2);
  u16*    tB     = (u16*)alloc((size_t)N_NODES * FDIM * 2);
  float*  hbuf   = (float*)alloc((size_t)N_NODES * NH * 4);
  float*  P2     = (float*)alloc((size_t)N_NODES * 4 * 4);
  float*  Q2     = (float*)alloc((size_t)N_NODES * 4 * 4);
  float*  R2     = (float*)alloc((size_t)N_NODES * 4 * 4);
  (void)ws_size; (void)in_sizes; (void)n_in; (void)out_size;

  hipMemsetAsync(gcur, 0, (size_t)NBUCK * 8 * 4, stream);
  hipMemsetAsync(stats, 0, 32 * 8, stream);

  bucket_scatter_kernel<<<NBLK1, 1024, 0, stream>>>(row, col, ea, gcur, bucketed);
  node_offs_csr_kernel<<<NBUCK, 1024, 0, stream>>>(bucketed, gcur, x, offs, dinv, zx, csr);

  const int NPB = 6250;  // N_NODES*16/256 exactly
  // conv1 layer 1 (rank-1 collapse): merged scalar prop + dense epilogue -> tA
  sprop_mid_kernel<<<NPB, 256, 0, stream>>>(csr, offs, zx, dinv, x, w1i, w1r, b1, w1, tA);
  // conv1 layers 2-4: combined 3-stack propagation; 6250 blocks = 4 nodes/wave
  conv1_prop_kernel<<<6250, 256, 0, stream>>>(tA, tB, nullptr, csr, offs, dinv, x, w1r, b1, w1, 1);
  conv1_prop_kernel<<<6250, 256, 0, stream>>>(tB, tA, nullptr, csr, offs, dinv, x, w1r, b1, w1, 1);
  conv1_prop_kernel<<<6250, 256, 0, stream>>>(tA, nullptr, hbuf, csr, offs, dinv, x, w1r, b1, w1, 0);

  bn_stats_kernel<<<(N_NODES + 255) / 256, 256, 0, stream>>>(hbuf, stats);
  bn_final_kernel<<<1, 64, 0, stream>>>(stats, bng, bnb, bnsc, bnsh);
  conv2_init_kernel<<<(N_NODES + 255) / 256, 256, 0, stream>>>(
      hbuf, bnsc, bnsh, dinv, w2i, w2r, b2, P2, R2);

  conv2_prop_kernel<<<NPB, 256, 0, stream>>>(P2, Q2, nullptr, csr, offs, dinv, R2, w2, 0, 0);
  conv2_prop_kernel<<<NPB, 256, 0, stream>>>(Q2, P2, nullptr, csr, offs, dinv, R2, w2, 1, 0);
  conv2_prop_kernel<<<NPB, 256, 0, stream>>>(P2, Q2, nullptr, csr, offs, dinv, R2, w2, 1, 0);
  conv2_prop_kernel<<<NPB, 256, 0, stream>>>(Q2, P2, y, csr, offs, dinv, R2, w2, 1, 1);
}